// Round 6
// baseline (789.948 us; speedup 1.0000x reference)
//
#include <hip/hip_runtime.h>

#define D      128
#define NCLI   100000
#define NAGG   1000
#define NLAYER 3
#define NBKT   782   // ceil(NCLI/128)
#define CPAD   132   // LDS C-tile row stride (padded: 2 lanes/bank max everywhere)

typedef short bf16x8 __attribute__((ext_vector_type(8)));
typedef float f32x4 __attribute__((ext_vector_type(4)));

static __device__ __forceinline__ float leaky(float x) { return x >= 0.f ? x : 0.1f * x; }

// ---- bf16 pack/unpack (RNE) ----
static __device__ __forceinline__ unsigned bf16_rn(float f) {
    unsigned u = __float_as_uint(f);
    return (u + 0x7fffu + ((u >> 16) & 1u)) >> 16;
}
static __device__ __forceinline__ float bf_val(unsigned h) { return __uint_as_float(h << 16); }
static __device__ __forceinline__ unsigned pack_bf2(float lo, float hi) {
    return bf16_rn(lo) | (bf16_rn(hi) << 16);
}
static __device__ __forceinline__ float bf_lo(unsigned v) { return __uint_as_float(v << 16); }
static __device__ __forceinline__ float bf_hi(unsigned v) { return __uint_as_float(v & 0xffff0000u); }

// ---------------- CSR build ----------------

__global__ __launch_bounds__(256) void hist_both(const int* __restrict__ c2a_dst,
                                                 const int* __restrict__ a2c_dst, int E,
                                                 int* __restrict__ cnt_a, int* __restrict__ bcnt) {
    __shared__ int h[NAGG + NBKT];
    for (int i = threadIdx.x; i < NAGG + NBKT; i += 256) h[i] = 0;
    __syncthreads();
    int stride = gridDim.x * 256;
    for (int e = blockIdx.x * 256 + threadIdx.x; e < E; e += stride) {
        atomicAdd(&h[c2a_dst[e]], 1);
        atomicAdd(&h[NAGG + (a2c_dst[e] >> 7)], 1);
    }
    __syncthreads();
    for (int i = threadIdx.x; i < NAGG; i += 256)
        if (h[i]) atomicAdd(&cnt_a[i], h[i]);
    for (int i = threadIdx.x; i < NBKT; i += 256)
        if (h[NAGG + i]) atomicAdd(&bcnt[i], h[NAGG + i]);
}

__global__ void scan_both(const int* __restrict__ cnt_a, int* __restrict__ rp_a,
                          int* __restrict__ cur_a, const int* __restrict__ bcnt,
                          int* __restrict__ brp, int* __restrict__ bcur) {
    __shared__ int sh[1024];
    const int* cnt;
    int *rp, *cur, n;
    if (blockIdx.x == 0) { cnt = cnt_a; rp = rp_a; cur = cur_a; n = NAGG; }
    else                 { cnt = bcnt;  rp = brp;  cur = bcur;  n = NBKT; }
    int t = threadIdx.x;
    int v = (t < n) ? cnt[t] : 0;
    sh[t] = v;
    __syncthreads();
    for (int off = 1; off < 1024; off <<= 1) {
        int x = (t >= off) ? sh[t - off] : 0;
        __syncthreads();
        sh[t] += x;
        __syncthreads();
    }
    if (t == 0) { rp[0] = 0; cur[0] = 0; }
    if (t < n) {
        rp[t + 1] = sh[t];
        if (t + 1 < n) cur[t + 1] = sh[t];
    }
}

__global__ __launch_bounds__(256) void scatter_c2a(const int* __restrict__ src,
                                                   const int* __restrict__ dst, int E,
                                                   int* __restrict__ cursor,
                                                   int* __restrict__ col) {
    __shared__ int h[NAGG];
    __shared__ int base[NAGG];
    int tid = threadIdx.x;
    int chunk = (E + gridDim.x - 1) / gridDim.x;
    int e0 = blockIdx.x * chunk;
    int e1 = min(E, e0 + chunk);
    for (int i = tid; i < NAGG; i += 256) h[i] = 0;
    __syncthreads();
    for (int e = e0 + tid; e < e1; e += 256) atomicAdd(&h[dst[e]], 1);
    __syncthreads();
    for (int i = tid; i < NAGG; i += 256) {
        int c = h[i];
        base[i] = c ? atomicAdd(&cursor[i], c) : 0;
    }
    __syncthreads();
    for (int e = e0 + tid; e < e1; e += 256) {
        int pos = atomicAdd(&base[dst[e]], 1);
        col[pos] = src[e];
    }
}

__global__ __launch_bounds__(256) void bucket_scatter(const int* __restrict__ src,
                                                      const int* __restrict__ dst, int E,
                                                      int* __restrict__ bcur,
                                                      int* __restrict__ sorted1) {
    __shared__ int h[NBKT];
    __shared__ int base[NBKT];
    int tid = threadIdx.x;
    int chunk = (E + gridDim.x - 1) / gridDim.x;
    int e0 = blockIdx.x * chunk;
    int e1 = min(E, e0 + chunk);
    for (int i = tid; i < NBKT; i += 256) h[i] = 0;
    __syncthreads();
    for (int e = e0 + tid; e < e1; e += 256) atomicAdd(&h[dst[e] >> 7], 1);
    __syncthreads();
    for (int i = tid; i < NBKT; i += 256) {
        int c = h[i];
        base[i] = c ? atomicAdd(&bcur[i], c) : 0;
    }
    __syncthreads();
    for (int e = e0 + tid; e < e1; e += 256) {
        int d = dst[e];
        int pos = atomicAdd(&base[d >> 7], 1);
        sorted1[pos] = ((d & 127) << 10) | src[e];
    }
}

__global__ __launch_bounds__(256) void bucket_csr(const int* __restrict__ brp,
                                                  const int* __restrict__ sorted1,
                                                  int* __restrict__ rp_c,
                                                  int* __restrict__ col) {
    __shared__ int h[128], cur[128];
    int b = blockIdx.x, tid = threadIdx.x;
    if (tid < 128) h[tid] = 0;
    __syncthreads();
    int beg = brp[b], end = brp[b + 1];
    for (int e = beg + tid; e < end; e += 256) atomicAdd(&h[sorted1[e] >> 10], 1);
    __syncthreads();
    if (tid < 128) cur[tid] = h[tid];
    __syncthreads();
    for (int off = 1; off < 128; off <<= 1) {
        int x = 0;
        if (tid < 128 && tid >= off) x = cur[tid - off];
        __syncthreads();
        if (tid < 128) cur[tid] += x;
        __syncthreads();
    }
    if (tid < 128) {
        int start = beg + cur[tid] - h[tid];
        int c = b * 128 + tid;
        if (c < NCLI) rp_c[c] = start;
        cur[tid] = start;
    }
    if (b == NBKT - 1 && tid == 0) rp_c[NCLI] = end;
    __syncthreads();
    for (int e = beg + tid; e < end; e += 256) {
        int p = sorted1[e];
        int pos = atomicAdd(&cur[p >> 10], 1);
        col[pos] = p & 1023;
    }
}

// ---------------- layer kernels ----------------

// x_clients f32 -> hi/lo bf16 tables
__global__ __launch_bounds__(256) void cvt_x(const float4* __restrict__ X4,
                                             uint2* __restrict__ hi, uint2* __restrict__ lo,
                                             int n4) {
    int t = blockIdx.x * 256 + threadIdx.x;
    if (t >= n4) return;
    float4 f = X4[t];
    unsigned h0 = bf16_rn(f.x), h1 = bf16_rn(f.y), h2 = bf16_rn(f.z), h3 = bf16_rn(f.w);
    hi[t] = make_uint2(h0 | (h1 << 16), h2 | (h3 << 16));
    lo[t] = make_uint2(pack_bf2(f.x - bf_val(h0), f.y - bf_val(h1)),
                       pack_bf2(f.z - bf_val(h2), f.w - bf_val(h3)));
}

// Wr_a2c (3 layers, [k][n]) -> transposed hi/lo bf16: Wt[l][0][n][k], Wt[l][1][n][k]
__global__ __launch_bounds__(256) void cvt_w(const float* __restrict__ W,
                                             unsigned short* __restrict__ Wt) {
    int idx = blockIdx.x * 256 + threadIdx.x;
    if (idx >= NLAYER * D * D) return;
    int layer = idx >> 14, rem = idx & (D * D - 1);
    int k = rem >> 7, n = rem & 127;
    float w = W[layer * D * D + k * D + n];
    unsigned h = bf16_rn(w);
    unsigned short* base = Wt + layer * 2 * D * D;
    base[n * D + k] = (unsigned short)h;
    base[D * D + n * D + k] = (unsigned short)bf16_rn(w - bf_val(h));
}

// Fused agg-side: mean gather (c2a) + ya = xa@Wl_a2c + xa_new = leaky(mean@Wl_c2a + xa@Wr_c2a + b)
__global__ __launch_bounds__(512) void agg_side(const unsigned* __restrict__ tbl,
                                                const int* __restrict__ rowptr,
                                                const int* __restrict__ col,
                                                const float* xa_old,
                                                const float* __restrict__ Wl_a2c,
                                                const float* __restrict__ Wl_c2a,
                                                const float* __restrict__ Wr_c2a,
                                                const float* __restrict__ b_c2a,
                                                unsigned short* __restrict__ ya_bf,
                                                float* xa_out) {
    __shared__ int cols[512];
    __shared__ float part[8][D];
    __shared__ float mr[D], xr[D];
    int i = blockIdx.x, tid = threadIdx.x;
    int g = tid >> 6, l = tid & 63;
    if (tid < D) xr[tid] = xa_old[i * D + tid];
    int beg = rowptr[i], end = rowptr[i + 1];
    float x0 = 0, y0 = 0, x1 = 0, y1 = 0, x2 = 0, y2 = 0, x3 = 0, y3 = 0;
    float x4 = 0, y4 = 0, x5 = 0, y5 = 0, x6 = 0, y6 = 0, x7 = 0, y7 = 0;
    for (int base = beg; base < end; base += 512) {
        int m = end - base;
        if (m > 512) m = 512;
        __syncthreads();
        if (tid < m) cols[tid] = col[base + tid];
        __syncthreads();
        int lo = g * 64;
        int hi = min(lo + 64, m);
        int t = lo;
        for (; t + 8 <= hi; t += 8) {
            unsigned v0 = tbl[(cols[t + 0] << 6) + l];
            unsigned v1 = tbl[(cols[t + 1] << 6) + l];
            unsigned v2 = tbl[(cols[t + 2] << 6) + l];
            unsigned v3 = tbl[(cols[t + 3] << 6) + l];
            unsigned v4 = tbl[(cols[t + 4] << 6) + l];
            unsigned v5 = tbl[(cols[t + 5] << 6) + l];
            unsigned v6 = tbl[(cols[t + 6] << 6) + l];
            unsigned v7 = tbl[(cols[t + 7] << 6) + l];
            x0 += bf_lo(v0); y0 += bf_hi(v0);
            x1 += bf_lo(v1); y1 += bf_hi(v1);
            x2 += bf_lo(v2); y2 += bf_hi(v2);
            x3 += bf_lo(v3); y3 += bf_hi(v3);
            x4 += bf_lo(v4); y4 += bf_hi(v4);
            x5 += bf_lo(v5); y5 += bf_hi(v5);
            x6 += bf_lo(v6); y6 += bf_hi(v6);
            x7 += bf_lo(v7); y7 += bf_hi(v7);
        }
        for (; t < hi; t++) {
            unsigned v = tbl[(cols[t] << 6) + l];
            x0 += bf_lo(v); y0 += bf_hi(v);
        }
    }
    part[g][2 * l]     = ((x0 + x1) + (x2 + x3)) + ((x4 + x5) + (x6 + x7));
    part[g][2 * l + 1] = ((y0 + y1) + (y2 + y3)) + ((y4 + y5) + (y6 + y7));
    __syncthreads();
    if (tid < D) {
        float tot = 0.f;
#pragma unroll
        for (int gg = 0; gg < 8; gg++) tot += part[gg][tid];
        mr[tid] = tot / fmaxf((float)(end - beg), 1.f);
    }
    __syncthreads();
    if (tid < D) {
        int j = tid;
        float accy = 0.f, accn = b_c2a[j];
#pragma unroll 4
        for (int k = 0; k < D; k++) {
            accy += xr[k] * Wl_a2c[k * D + j];
            accn += mr[k] * Wl_c2a[k * D + j] + xr[k] * Wr_c2a[k * D + j];
        }
        ya_bf[i * D + j] = (unsigned short)bf16_rn(accy);
        xa_out[i * D + j] = leaky(accn);
    }
}

// Fused: C = (Ahi+Alo)@(Whi+Wlo)+bias (split-bf16 MFMA, C parked in LDS), then per-row
// ya-mean gather + leaky epilogue. LAST=0 writes xc hi/lo tables; LAST=1 fuses linear head.
// Block: 4 waves, 64 rows x 128 cols.
template <int LAST>
__global__ __launch_bounds__(256) void gemm_agg(const unsigned short* __restrict__ Ahi,
                                                const unsigned short* __restrict__ Alo,
                                                const unsigned short* __restrict__ Wt,
                                                const float* __restrict__ bias,
                                                const unsigned* __restrict__ ya,
                                                const int* __restrict__ rp_c,
                                                const int* __restrict__ col,
                                                unsigned* __restrict__ xhi,
                                                unsigned* __restrict__ xlo,
                                                const float* __restrict__ Wlin,
                                                const float* __restrict__ blin,
                                                float* __restrict__ out, int E) {
    __shared__ float Csh[64 * CPAD];
    int tid = threadIdx.x;
    int wave = tid >> 6, lane = tid & 63;
    int t = lane & 15, q = lane >> 4;
    // ---- phase 1: MFMA ----
    {
        int m = blockIdx.x * 64 + wave * 16 + t;
        int mc = min(m, NCLI - 1);
        const unsigned short* arh = Ahi + (size_t)mc * D + q * 8;
        const unsigned short* arl = Alo + (size_t)mc * D + q * 8;
        bf16x8 ahi[4], alo[4];
#pragma unroll
        for (int kc = 0; kc < 4; kc++) {
            ahi[kc] = *(const bf16x8*)(arh + kc * 32);
            alo[kc] = *(const bf16x8*)(arl + kc * 32);
        }
        const unsigned short* Wlo = Wt + D * D;
        f32x4 acc[8];
#pragma unroll
        for (int nt = 0; nt < 8; nt++) {
            float bv = bias[nt * 16 + t];
            acc[nt] = (f32x4){bv, bv, bv, bv};
        }
#pragma unroll
        for (int nt = 0; nt < 8; nt++) {
            const unsigned short* brh = Wt + (size_t)(nt * 16 + t) * D + q * 8;
            const unsigned short* brl = Wlo + (size_t)(nt * 16 + t) * D + q * 8;
            bf16x8 bhi[4], blo[4];
#pragma unroll
            for (int kc = 0; kc < 4; kc++) {
                bhi[kc] = *(const bf16x8*)(brh + kc * 32);
                blo[kc] = *(const bf16x8*)(brl + kc * 32);
            }
#pragma unroll
            for (int kc = 0; kc < 4; kc++) {
                acc[nt] = __builtin_amdgcn_mfma_f32_16x16x32_bf16(ahi[kc], bhi[kc], acc[nt], 0, 0, 0);
                acc[nt] = __builtin_amdgcn_mfma_f32_16x16x32_bf16(alo[kc], bhi[kc], acc[nt], 0, 0, 0);
                acc[nt] = __builtin_amdgcn_mfma_f32_16x16x32_bf16(ahi[kc], blo[kc], acc[nt], 0, 0, 0);
            }
        }
        // park C in LDS: local row = wave*16 + q*4 + reg, col = nt*16 + t
        int lrow = wave * 16 + q * 4;
#pragma unroll
        for (int reg = 0; reg < 4; reg++) {
            float* cr = Csh + (lrow + reg) * CPAD + t;
#pragma unroll
            for (int nt = 0; nt < 8; nt++) cr[nt * 16] = acc[nt][reg];
        }
    }
    __syncthreads();
    // ---- phase 2: per-row ya-mean + leaky epilogue (one row at a time per wave) ----
    int l = lane;
    for (int rr = 0; rr < 16; rr++) {
        int gid = blockIdx.x * 64 + wave * 16 + rr;
        if (gid >= NCLI) break;
        int beg = rp_c[gid], end = rp_c[gid + 1];
        float a0 = 0, b0 = 0, a1 = 0, b1 = 0, a2 = 0, b2 = 0, a3 = 0, b3 = 0;
        float a4 = 0, b4 = 0, a5 = 0, b5 = 0, a6 = 0, b6 = 0, a7 = 0, b7 = 0;
        for (int ch = beg; ch < end; ch += 64) {
            int len = min(64, end - ch);
            int ec = col[min(ch + l, E - 1)];
            int j = 0;
            for (; j + 8 <= len; j += 8) {
                int r0 = __shfl(ec, j + 0), r1 = __shfl(ec, j + 1);
                int r2 = __shfl(ec, j + 2), r3 = __shfl(ec, j + 3);
                int r4 = __shfl(ec, j + 4), r5 = __shfl(ec, j + 5);
                int r6 = __shfl(ec, j + 6), r7 = __shfl(ec, j + 7);
                unsigned v0 = ya[(r0 << 6) + l];
                unsigned v1 = ya[(r1 << 6) + l];
                unsigned v2 = ya[(r2 << 6) + l];
                unsigned v3 = ya[(r3 << 6) + l];
                unsigned v4 = ya[(r4 << 6) + l];
                unsigned v5 = ya[(r5 << 6) + l];
                unsigned v6 = ya[(r6 << 6) + l];
                unsigned v7 = ya[(r7 << 6) + l];
                a0 += bf_lo(v0); b0 += bf_hi(v0);
                a1 += bf_lo(v1); b1 += bf_hi(v1);
                a2 += bf_lo(v2); b2 += bf_hi(v2);
                a3 += bf_lo(v3); b3 += bf_hi(v3);
                a4 += bf_lo(v4); b4 += bf_hi(v4);
                a5 += bf_lo(v5); b5 += bf_hi(v5);
                a6 += bf_lo(v6); b6 += bf_hi(v6);
                a7 += bf_lo(v7); b7 += bf_hi(v7);
            }
            for (; j < len; j++) {
                int r = __shfl(ec, j);
                unsigned v = ya[(r << 6) + l];
                a0 += bf_lo(v); b0 += bf_hi(v);
            }
        }
        float sx = ((a0 + a1) + (a2 + a3)) + ((a4 + a5) + (a6 + a7));
        float sy = ((b0 + b1) + (b2 + b3)) + ((b4 + b5) + (b6 + b7));
        float inv = 1.f / fmaxf((float)(end - beg), 1.f);
        float2 yv = *(const float2*)&Csh[(wave * 16 + rr) * CPAD + 2 * l];
        float r0 = leaky(yv.x + sx * inv);
        float r1 = leaky(yv.y + sy * inv);
        if (LAST) {
            float2 w = *(const float2*)&Wlin[2 * l];
            float v = r0 * w.x + r1 * w.y;
#pragma unroll
            for (int off = 32; off > 0; off >>= 1) v += __shfl_down(v, off);
            if (l == 0) out[gid] = v + blin[0];
        } else {
            unsigned h0 = bf16_rn(r0), h1 = bf16_rn(r1);
            xhi[(gid << 6) + l] = h0 | (h1 << 16);
            xlo[(gid << 6) + l] = pack_bf2(r0 - bf_val(h0), r1 - bf_val(h1));
        }
    }
}

extern "C" void kernel_launch(void* const* d_in, const int* in_sizes, int n_in,
                              void* d_out, int out_size, void* d_ws, size_t ws_size,
                              hipStream_t stream) {
    const float* x_clients = (const float*)d_in[0];
    const float* x_agg     = (const float*)d_in[1];
    const int*   c2a_src   = (const int*)d_in[2];
    const int*   c2a_dst   = (const int*)d_in[3];
    const int*   a2c_src   = (const int*)d_in[4];
    const int*   a2c_dst   = (const int*)d_in[5];
    const float* Wl_c2a    = (const float*)d_in[6];
    const float* Wr_c2a    = (const float*)d_in[7];
    const float* b_c2a     = (const float*)d_in[8];
    const float* Wl_a2c    = (const float*)d_in[9];
    const float* Wr_a2c    = (const float*)d_in[10];
    const float* b_a2c     = (const float*)d_in[11];
    const float* W_lin     = (const float*)d_in[12];
    const float* b_lin     = (const float*)d_in[13];
    float* out = (float*)d_out;
    const int E = in_sizes[2];

    char* p = (char*)d_ws;
    auto alloc = [&](size_t bytes) {
        char* r = p;
        p += (bytes + 255) & ~(size_t)255;
        return r;
    };
    unsigned* xc_hi = (unsigned*)alloc(sizeof(unsigned) * NCLI * 64);  // bf16 hi (also gather tbl)
    unsigned* xc_lo = (unsigned*)alloc(sizeof(unsigned) * NCLI * 64);  // bf16 lo
    float*    xa    = (float*)alloc(sizeof(float) * NAGG * D);
    unsigned short* ya_bf = (unsigned short*)alloc(sizeof(unsigned short) * NAGG * D);
    unsigned short* Wt = (unsigned short*)alloc(sizeof(unsigned short) * NLAYER * 2 * D * D);
    int* cnt_a = (int*)alloc(sizeof(int) * 2048);  // cnt_a[0..1023] + bcnt[1024..]
    int* bcnt  = cnt_a + 1024;
    int* rp_a  = (int*)alloc(sizeof(int) * (NAGG + 1));
    int* cur_a = (int*)alloc(sizeof(int) * NAGG);
    int* brp   = (int*)alloc(sizeof(int) * (NBKT + 1));
    int* bcur  = (int*)alloc(sizeof(int) * NBKT);
    int* rp_c  = (int*)alloc(sizeof(int) * (NCLI + 1));
    int* col_c2a = (int*)alloc(sizeof(int) * E);
    int* col_a2c = (int*)alloc(sizeof(int) * E);
    // sorted1 aliases xc_lo: lifetime disjoint (CSR build completes before cvt_x writes xc_lo)
    int* sorted1 = (int*)xc_lo;

    hipMemsetAsync(cnt_a, 0, sizeof(int) * 2048, stream);

    // CSR build first (sorted1 occupies xc_lo until bucket_csr finishes)
    hist_both<<<512, 256, 0, stream>>>(c2a_dst, a2c_dst, E, cnt_a, bcnt);
    scan_both<<<2, 1024, 0, stream>>>(cnt_a, rp_a, cur_a, bcnt, brp, bcur);
    scatter_c2a<<<256, 256, 0, stream>>>(c2a_src, c2a_dst, E, cur_a, col_c2a);
    bucket_scatter<<<256, 256, 0, stream>>>(a2c_src, a2c_dst, E, bcur, sorted1);
    bucket_csr<<<NBKT, 256, 0, stream>>>(brp, sorted1, rp_c, col_a2c);

    // feature/weight conversion (after CSR: cvt_x overwrites sorted1's region)
    cvt_x<<<(NCLI * D / 4 + 255) / 256, 256, 0, stream>>>((const float4*)x_clients,
                                                          (uint2*)xc_hi, (uint2*)xc_lo,
                                                          NCLI * D / 4);
    cvt_w<<<(NLAYER * D * D + 255) / 256, 256, 0, stream>>>(Wr_a2c, Wt);

    const float* xa_old = x_agg;
    for (int l = 0; l < NLAYER; l++) {
        // agg side: mean(c2a) + ya_bf + xa update, one kernel
        agg_side<<<NAGG, 512, 0, stream>>>(xc_hi, rp_a, col_c2a, xa_old,
                                           Wl_a2c + l * D * D, Wl_c2a + l * D * D,
                                           Wr_c2a + l * D * D, b_c2a + l * D, ya_bf, xa);
        // fused: xc = leaky(xc@Wr_a2c + b + mean ya); last layer also applies linear head
        if (l < NLAYER - 1) {
            gemm_agg<0><<<(NCLI + 63) / 64, 256, 0, stream>>>(
                (const unsigned short*)xc_hi, (const unsigned short*)xc_lo,
                Wt + l * 2 * D * D, b_a2c + l * D, (const unsigned*)ya_bf, rp_c, col_a2c,
                xc_hi, xc_lo, nullptr, nullptr, nullptr, E);
        } else {
            gemm_agg<1><<<(NCLI + 63) / 64, 256, 0, stream>>>(
                (const unsigned short*)xc_hi, (const unsigned short*)xc_lo,
                Wt + l * 2 * D * D, b_a2c + l * D, (const unsigned*)ya_bf, rp_c, col_a2c,
                nullptr, nullptr, W_lin, b_lin, out, E);
        }
        xa_old = xa;
    }
}

// Round 7
// 745.255 us; speedup vs baseline: 1.0600x; 1.0600x over previous
//
#include <hip/hip_runtime.h>

#define D      128
#define NCLI   100000
#define NAGG   1000
#define NLAYER 3
#define NBKT   782   // ceil(NCLI/128)
#define NGEMM  ((NCLI + 63) / 64)   // 1563 gemm blocks (64 rows each)

typedef short bf16x8 __attribute__((ext_vector_type(8)));
typedef float f32x4 __attribute__((ext_vector_type(4)));

static __device__ __forceinline__ float leaky(float x) { return x >= 0.f ? x : 0.1f * x; }

// ---- bf16 pack/unpack (RNE) ----
static __device__ __forceinline__ unsigned bf16_rn(float f) {
    unsigned u = __float_as_uint(f);
    return (u + 0x7fffu + ((u >> 16) & 1u)) >> 16;
}
static __device__ __forceinline__ float bf_val(unsigned h) { return __uint_as_float(h << 16); }
static __device__ __forceinline__ unsigned pack_bf2(float lo, float hi) {
    return bf16_rn(lo) | (bf16_rn(hi) << 16);
}
static __device__ __forceinline__ float bf_lo(unsigned v) { return __uint_as_float(v << 16); }
static __device__ __forceinline__ float bf_hi(unsigned v) { return __uint_as_float(v & 0xffff0000u); }

// ---------------- CSR build ----------------

__global__ __launch_bounds__(256) void hist_both(const int* __restrict__ c2a_dst,
                                                 const int* __restrict__ a2c_dst, int E,
                                                 int* __restrict__ cnt_a, int* __restrict__ bcnt) {
    __shared__ int h[NAGG + NBKT];
    for (int i = threadIdx.x; i < NAGG + NBKT; i += 256) h[i] = 0;
    __syncthreads();
    int stride = gridDim.x * 256;
    for (int e = blockIdx.x * 256 + threadIdx.x; e < E; e += stride) {
        atomicAdd(&h[c2a_dst[e]], 1);
        atomicAdd(&h[NAGG + (a2c_dst[e] >> 7)], 1);
    }
    __syncthreads();
    for (int i = threadIdx.x; i < NAGG; i += 256)
        if (h[i]) atomicAdd(&cnt_a[i], h[i]);
    for (int i = threadIdx.x; i < NBKT; i += 256)
        if (h[NAGG + i]) atomicAdd(&bcnt[i], h[NAGG + i]);
}

__global__ void scan_both(const int* __restrict__ cnt_a, int* __restrict__ rp_a,
                          int* __restrict__ cur_a, const int* __restrict__ bcnt,
                          int* __restrict__ brp, int* __restrict__ bcur) {
    __shared__ int sh[1024];
    const int* cnt;
    int *rp, *cur, n;
    if (blockIdx.x == 0) { cnt = cnt_a; rp = rp_a; cur = cur_a; n = NAGG; }
    else                 { cnt = bcnt;  rp = brp;  cur = bcur;  n = NBKT; }
    int t = threadIdx.x;
    int v = (t < n) ? cnt[t] : 0;
    sh[t] = v;
    __syncthreads();
    for (int off = 1; off < 1024; off <<= 1) {
        int x = (t >= off) ? sh[t - off] : 0;
        __syncthreads();
        sh[t] += x;
        __syncthreads();
    }
    if (t == 0) { rp[0] = 0; cur[0] = 0; }
    if (t < n) {
        rp[t + 1] = sh[t];
        if (t + 1 < n) cur[t + 1] = sh[t];
    }
}

__global__ __launch_bounds__(256) void scatter_c2a(const int* __restrict__ src,
                                                   const int* __restrict__ dst, int E,
                                                   int* __restrict__ cursor,
                                                   int* __restrict__ col) {
    __shared__ int h[NAGG];
    __shared__ int base[NAGG];
    int tid = threadIdx.x;
    int chunk = (E + gridDim.x - 1) / gridDim.x;
    int e0 = blockIdx.x * chunk;
    int e1 = min(E, e0 + chunk);
    for (int i = tid; i < NAGG; i += 256) h[i] = 0;
    __syncthreads();
    for (int e = e0 + tid; e < e1; e += 256) atomicAdd(&h[dst[e]], 1);
    __syncthreads();
    for (int i = tid; i < NAGG; i += 256) {
        int c = h[i];
        base[i] = c ? atomicAdd(&cursor[i], c) : 0;
    }
    __syncthreads();
    for (int e = e0 + tid; e < e1; e += 256) {
        int pos = atomicAdd(&base[dst[e]], 1);
        col[pos] = src[e];
    }
}

__global__ __launch_bounds__(256) void bucket_scatter(const int* __restrict__ src,
                                                      const int* __restrict__ dst, int E,
                                                      int* __restrict__ bcur,
                                                      int* __restrict__ sorted1) {
    __shared__ int h[NBKT];
    __shared__ int base[NBKT];
    int tid = threadIdx.x;
    int chunk = (E + gridDim.x - 1) / gridDim.x;
    int e0 = blockIdx.x * chunk;
    int e1 = min(E, e0 + chunk);
    for (int i = tid; i < NBKT; i += 256) h[i] = 0;
    __syncthreads();
    for (int e = e0 + tid; e < e1; e += 256) atomicAdd(&h[dst[e] >> 7], 1);
    __syncthreads();
    for (int i = tid; i < NBKT; i += 256) {
        int c = h[i];
        base[i] = c ? atomicAdd(&bcur[i], c) : 0;
    }
    __syncthreads();
    for (int e = e0 + tid; e < e1; e += 256) {
        int d = dst[e];
        int pos = atomicAdd(&base[d >> 7], 1);
        sorted1[pos] = ((d & 127) << 10) | src[e];
    }
}

__global__ __launch_bounds__(256) void bucket_csr(const int* __restrict__ brp,
                                                  const int* __restrict__ sorted1,
                                                  int* __restrict__ rp_c,
                                                  int* __restrict__ col) {
    __shared__ int h[128], cur[128];
    int b = blockIdx.x, tid = threadIdx.x;
    if (tid < 128) h[tid] = 0;
    __syncthreads();
    int beg = brp[b], end = brp[b + 1];
    for (int e = beg + tid; e < end; e += 256) atomicAdd(&h[sorted1[e] >> 10], 1);
    __syncthreads();
    if (tid < 128) cur[tid] = h[tid];
    __syncthreads();
    for (int off = 1; off < 128; off <<= 1) {
        int x = 0;
        if (tid < 128 && tid >= off) x = cur[tid - off];
        __syncthreads();
        if (tid < 128) cur[tid] += x;
        __syncthreads();
    }
    if (tid < 128) {
        int start = beg + cur[tid] - h[tid];
        int c = b * 128 + tid;
        if (c < NCLI) rp_c[c] = start;
        cur[tid] = start;
    }
    if (b == NBKT - 1 && tid == 0) rp_c[NCLI] = end;
    __syncthreads();
    for (int e = beg + tid; e < end; e += 256) {
        int p = sorted1[e];
        int pos = atomicAdd(&cur[p >> 10], 1);
        col[pos] = p & 1023;
    }
}

// ---------------- layer kernels ----------------

// x_clients f32 -> hi/lo bf16 tables
__global__ __launch_bounds__(256) void cvt_x(const float4* __restrict__ X4,
                                             uint2* __restrict__ hi, uint2* __restrict__ lo,
                                             int n4) {
    int t = blockIdx.x * 256 + threadIdx.x;
    if (t >= n4) return;
    float4 f = X4[t];
    unsigned h0 = bf16_rn(f.x), h1 = bf16_rn(f.y), h2 = bf16_rn(f.z), h3 = bf16_rn(f.w);
    hi[t] = make_uint2(h0 | (h1 << 16), h2 | (h3 << 16));
    lo[t] = make_uint2(pack_bf2(f.x - bf_val(h0), f.y - bf_val(h1)),
                       pack_bf2(f.z - bf_val(h2), f.w - bf_val(h3)));
}

// Wr_a2c (3 layers, [k][n]) -> transposed hi/lo bf16: Wt[l][0][n][k], Wt[l][1][n][k]
__global__ __launch_bounds__(256) void cvt_w(const float* __restrict__ W,
                                             unsigned short* __restrict__ Wt) {
    int idx = blockIdx.x * 256 + threadIdx.x;
    if (idx >= NLAYER * D * D) return;
    int layer = idx >> 14, rem = idx & (D * D - 1);
    int k = rem >> 7, n = rem & 127;
    float w = W[layer * D * D + k * D + n];
    unsigned h = bf16_rn(w);
    unsigned short* base = Wt + layer * 2 * D * D;
    base[n * D + k] = (unsigned short)h;
    base[D * D + n * D + k] = (unsigned short)bf16_rn(w - bf_val(h));
}

// ONE launch per layer: blocks [0,NAGG) run the agg-side (mean gather + ya + xa update),
// blocks [NAGG, NAGG+NGEMM) run the split-bf16 MFMA gemm Yb = xc@Wr + b.
// The two halves are data-independent (both only read xc tables) and co-schedule:
// gemm's A-stream latency hides behind agg_side's gather latency and vice versa.
__global__ __launch_bounds__(256) void layer_par(
    // agg_side args
    const unsigned* __restrict__ tbl, const int* __restrict__ rp_a,
    const int* __restrict__ col_c2a, const float* xa_old,
    const float* __restrict__ Wl_a2c, const float* __restrict__ Wl_c2a,
    const float* __restrict__ Wr_c2a, const float* __restrict__ b_c2a,
    unsigned short* __restrict__ ya_bf, float* xa_out,
    // gemm args
    const unsigned short* __restrict__ Ahi, const unsigned short* __restrict__ Alo,
    const unsigned short* __restrict__ Wt, const float* __restrict__ bias,
    float* __restrict__ Yb) {
    if (blockIdx.x < NAGG) {
        // ---- agg_side: 256 threads = 4 groups x 64 lanes ----
        __shared__ int cols[256];
        __shared__ float part[4][D];
        __shared__ float mr[D], xr[D];
        int i = blockIdx.x, tid = threadIdx.x;
        int g = tid >> 6, l = tid & 63;
        if (tid < D) xr[tid] = xa_old[i * D + tid];
        int beg = rp_a[i], end = rp_a[i + 1];
        float x0 = 0, y0 = 0, x1 = 0, y1 = 0, x2 = 0, y2 = 0, x3 = 0, y3 = 0;
        float x4 = 0, y4 = 0, x5 = 0, y5 = 0, x6 = 0, y6 = 0, x7 = 0, y7 = 0;
        for (int base = beg; base < end; base += 256) {
            int m = end - base;
            if (m > 256) m = 256;
            __syncthreads();
            if (tid < m) cols[tid] = col_c2a[base + tid];
            __syncthreads();
            int lo = g * 64;
            int hi = min(lo + 64, m);
            int t = lo;
            for (; t + 8 <= hi; t += 8) {
                unsigned v0 = tbl[(cols[t + 0] << 6) + l];
                unsigned v1 = tbl[(cols[t + 1] << 6) + l];
                unsigned v2 = tbl[(cols[t + 2] << 6) + l];
                unsigned v3 = tbl[(cols[t + 3] << 6) + l];
                unsigned v4 = tbl[(cols[t + 4] << 6) + l];
                unsigned v5 = tbl[(cols[t + 5] << 6) + l];
                unsigned v6 = tbl[(cols[t + 6] << 6) + l];
                unsigned v7 = tbl[(cols[t + 7] << 6) + l];
                x0 += bf_lo(v0); y0 += bf_hi(v0);
                x1 += bf_lo(v1); y1 += bf_hi(v1);
                x2 += bf_lo(v2); y2 += bf_hi(v2);
                x3 += bf_lo(v3); y3 += bf_hi(v3);
                x4 += bf_lo(v4); y4 += bf_hi(v4);
                x5 += bf_lo(v5); y5 += bf_hi(v5);
                x6 += bf_lo(v6); y6 += bf_hi(v6);
                x7 += bf_lo(v7); y7 += bf_hi(v7);
            }
            for (; t < hi; t++) {
                unsigned v = tbl[(cols[t] << 6) + l];
                x0 += bf_lo(v); y0 += bf_hi(v);
            }
        }
        part[g][2 * l]     = ((x0 + x1) + (x2 + x3)) + ((x4 + x5) + (x6 + x7));
        part[g][2 * l + 1] = ((y0 + y1) + (y2 + y3)) + ((y4 + y5) + (y6 + y7));
        __syncthreads();
        if (tid < D) {
            float tot = (part[0][tid] + part[1][tid]) + (part[2][tid] + part[3][tid]);
            mr[tid] = tot / fmaxf((float)(end - beg), 1.f);
        }
        __syncthreads();
        if (tid < D) {
            int j = tid;
            float accy = 0.f, accn = b_c2a[j];
#pragma unroll 4
            for (int k = 0; k < D; k++) {
                accy += xr[k] * Wl_a2c[k * D + j];
                accn += mr[k] * Wl_c2a[k * D + j] + xr[k] * Wr_c2a[k * D + j];
            }
            ya_bf[i * D + j] = (unsigned short)bf16_rn(accy);
            xa_out[i * D + j] = leaky(accn);
        }
    } else {
        // ---- gemm: 4 waves, 64 rows x 128 cols, no LDS ----
        int bid = blockIdx.x - NAGG;
        int tid = threadIdx.x;
        int wave = tid >> 6, lane = tid & 63;
        int t = lane & 15, q = lane >> 4;
        int m = bid * 64 + wave * 16 + t;
        int mc = min(m, NCLI - 1);
        const unsigned short* arh = Ahi + (size_t)mc * D + q * 8;
        const unsigned short* arl = Alo + (size_t)mc * D + q * 8;
        bf16x8 ahi[4], alo[4];
#pragma unroll
        for (int kc = 0; kc < 4; kc++) {
            ahi[kc] = *(const bf16x8*)(arh + kc * 32);
            alo[kc] = *(const bf16x8*)(arl + kc * 32);
        }
        const unsigned short* Wlo = Wt + D * D;
        f32x4 acc[8];
#pragma unroll
        for (int nt = 0; nt < 8; nt++) {
            float bv = bias[nt * 16 + t];
            acc[nt] = (f32x4){bv, bv, bv, bv};
        }
#pragma unroll
        for (int nt = 0; nt < 8; nt++) {
            const unsigned short* brh = Wt + (size_t)(nt * 16 + t) * D + q * 8;
            const unsigned short* brl = Wlo + (size_t)(nt * 16 + t) * D + q * 8;
            bf16x8 bhi[4], blo[4];
#pragma unroll
            for (int kc = 0; kc < 4; kc++) {
                bhi[kc] = *(const bf16x8*)(brh + kc * 32);
                blo[kc] = *(const bf16x8*)(brl + kc * 32);
            }
#pragma unroll
            for (int kc = 0; kc < 4; kc++) {
                acc[nt] = __builtin_amdgcn_mfma_f32_16x16x32_bf16(ahi[kc], bhi[kc], acc[nt], 0, 0, 0);
                acc[nt] = __builtin_amdgcn_mfma_f32_16x16x32_bf16(alo[kc], bhi[kc], acc[nt], 0, 0, 0);
                acc[nt] = __builtin_amdgcn_mfma_f32_16x16x32_bf16(ahi[kc], blo[kc], acc[nt], 0, 0, 0);
            }
        }
        int row0 = bid * 64 + wave * 16 + q * 4;
#pragma unroll
        for (int reg = 0; reg < 4; reg++) {
            int row = row0 + reg;
            if (row < NCLI) {
                float* yr = Yb + (size_t)row * D + t;
#pragma unroll
                for (int nt = 0; nt < 8; nt++) yr[nt * 16] = acc[nt][reg];
            }
        }
    }
}

// xc = leaky(Yb + mean_e ya_bf[col[e]]); writes hi/lo tables (LAST=0) or fused head (LAST=1)
template <int LAST>
__global__ __launch_bounds__(256) void agg_c_bf(const unsigned* __restrict__ ya,
                                                const int* __restrict__ rowptr,
                                                const int* __restrict__ col,
                                                const float* __restrict__ Y,
                                                unsigned* __restrict__ xhi,
                                                unsigned* __restrict__ xlo,
                                                const float* __restrict__ Wlin,
                                                const float* __restrict__ blin,
                                                float* __restrict__ out, int E) {
    int l = threadIdx.x & 63;
    int gid = blockIdx.x * 4 + (threadIdx.x >> 6);
    if (gid >= NCLI) return;
    int beg = rowptr[gid], end = rowptr[gid + 1];
    float a0 = 0, b0 = 0, a1 = 0, b1 = 0, a2 = 0, b2 = 0, a3 = 0, b3 = 0;
    float a4 = 0, b4 = 0, a5 = 0, b5 = 0, a6 = 0, b6 = 0, a7 = 0, b7 = 0;
    for (int ch = beg; ch < end; ch += 64) {
        int len = min(64, end - ch);
        int ec = col[min(ch + l, E - 1)];
        int j = 0;
        for (; j + 8 <= len; j += 8) {
            int r0 = __shfl(ec, j + 0), r1 = __shfl(ec, j + 1);
            int r2 = __shfl(ec, j + 2), r3 = __shfl(ec, j + 3);
            int r4 = __shfl(ec, j + 4), r5 = __shfl(ec, j + 5);
            int r6 = __shfl(ec, j + 6), r7 = __shfl(ec, j + 7);
            unsigned v0 = ya[(r0 << 6) + l];
            unsigned v1 = ya[(r1 << 6) + l];
            unsigned v2 = ya[(r2 << 6) + l];
            unsigned v3 = ya[(r3 << 6) + l];
            unsigned v4 = ya[(r4 << 6) + l];
            unsigned v5 = ya[(r5 << 6) + l];
            unsigned v6 = ya[(r6 << 6) + l];
            unsigned v7 = ya[(r7 << 6) + l];
            a0 += bf_lo(v0); b0 += bf_hi(v0);
            a1 += bf_lo(v1); b1 += bf_hi(v1);
            a2 += bf_lo(v2); b2 += bf_hi(v2);
            a3 += bf_lo(v3); b3 += bf_hi(v3);
            a4 += bf_lo(v4); b4 += bf_hi(v4);
            a5 += bf_lo(v5); b5 += bf_hi(v5);
            a6 += bf_lo(v6); b6 += bf_hi(v6);
            a7 += bf_lo(v7); b7 += bf_hi(v7);
        }
        for (; j < len; j++) {
            int r = __shfl(ec, j);
            unsigned v = ya[(r << 6) + l];
            a0 += bf_lo(v); b0 += bf_hi(v);
        }
    }
    float sx = ((a0 + a1) + (a2 + a3)) + ((a4 + a5) + (a6 + a7));
    float sy = ((b0 + b1) + (b2 + b3)) + ((b4 + b5) + (b6 + b7));
    float inv = 1.f / fmaxf((float)(end - beg), 1.f);
    float2 yv = *(const float2*)&Y[gid * D + 2 * l];
    float r0 = leaky(yv.x + sx * inv);
    float r1 = leaky(yv.y + sy * inv);
    if (LAST) {
        float2 w = *(const float2*)&Wlin[2 * l];
        float v = r0 * w.x + r1 * w.y;
#pragma unroll
        for (int off = 32; off > 0; off >>= 1) v += __shfl_down(v, off);
        if (l == 0) out[gid] = v + blin[0];
    } else {
        unsigned h0 = bf16_rn(r0), h1 = bf16_rn(r1);
        xhi[(gid << 6) + l] = h0 | (h1 << 16);
        xlo[(gid << 6) + l] = pack_bf2(r0 - bf_val(h0), r1 - bf_val(h1));
    }
}

extern "C" void kernel_launch(void* const* d_in, const int* in_sizes, int n_in,
                              void* d_out, int out_size, void* d_ws, size_t ws_size,
                              hipStream_t stream) {
    const float* x_clients = (const float*)d_in[0];
    const float* x_agg     = (const float*)d_in[1];
    const int*   c2a_src   = (const int*)d_in[2];
    const int*   c2a_dst   = (const int*)d_in[3];
    const int*   a2c_src   = (const int*)d_in[4];
    const int*   a2c_dst   = (const int*)d_in[5];
    const float* Wl_c2a    = (const float*)d_in[6];
    const float* Wr_c2a    = (const float*)d_in[7];
    const float* b_c2a     = (const float*)d_in[8];
    const float* Wl_a2c    = (const float*)d_in[9];
    const float* Wr_a2c    = (const float*)d_in[10];
    const float* b_a2c     = (const float*)d_in[11];
    const float* W_lin     = (const float*)d_in[12];
    const float* b_lin     = (const float*)d_in[13];
    float* out = (float*)d_out;
    const int E = in_sizes[2];

    char* p = (char*)d_ws;
    auto alloc = [&](size_t bytes) {
        char* r = p;
        p += (bytes + 255) & ~(size_t)255;
        return r;
    };
    float*    Yb    = (float*)alloc(sizeof(float) * NCLI * D);         // gemm output (f32)
    unsigned* xc_hi = (unsigned*)alloc(sizeof(unsigned) * NCLI * 64);  // bf16 hi (also gather tbl)
    unsigned* xc_lo = (unsigned*)alloc(sizeof(unsigned) * NCLI * 64);  // bf16 lo
    float*    xa    = (float*)alloc(sizeof(float) * NAGG * D);
    unsigned short* ya_bf = (unsigned short*)alloc(sizeof(unsigned short) * NAGG * D);
    unsigned short* Wt = (unsigned short*)alloc(sizeof(unsigned short) * NLAYER * 2 * D * D);
    int* cnt_a = (int*)alloc(sizeof(int) * 2048);  // cnt_a[0..1023] + bcnt[1024..]
    int* bcnt  = cnt_a + 1024;
    int* rp_a  = (int*)alloc(sizeof(int) * (NAGG + 1));
    int* cur_a = (int*)alloc(sizeof(int) * NAGG);
    int* brp   = (int*)alloc(sizeof(int) * (NBKT + 1));
    int* bcur  = (int*)alloc(sizeof(int) * NBKT);
    int* rp_c  = (int*)alloc(sizeof(int) * (NCLI + 1));
    int* col_c2a = (int*)alloc(sizeof(int) * E);
    int* col_a2c = (int*)alloc(sizeof(int) * E);
    // sorted1 aliases Yb: lifetime disjoint (CSR build completes before layer-0 gemm writes Yb)
    int* sorted1 = (int*)Yb;

    hipMemsetAsync(cnt_a, 0, sizeof(int) * 2048, stream);

    cvt_x<<<(NCLI * D / 4 + 255) / 256, 256, 0, stream>>>((const float4*)x_clients,
                                                          (uint2*)xc_hi, (uint2*)xc_lo,
                                                          NCLI * D / 4);
    cvt_w<<<(NLAYER * D * D + 255) / 256, 256, 0, stream>>>(Wr_a2c, Wt);

    hist_both<<<512, 256, 0, stream>>>(c2a_dst, a2c_dst, E, cnt_a, bcnt);
    scan_both<<<2, 1024, 0, stream>>>(cnt_a, rp_a, cur_a, bcnt, brp, bcur);
    scatter_c2a<<<256, 256, 0, stream>>>(c2a_src, c2a_dst, E, cur_a, col_c2a);
    bucket_scatter<<<256, 256, 0, stream>>>(a2c_src, a2c_dst, E, bcur, sorted1);
    bucket_csr<<<NBKT, 256, 0, stream>>>(brp, sorted1, rp_c, col_a2c);

    const float* xa_old = x_agg;
    for (int l = 0; l < NLAYER; l++) {
        // agg_side(l) + gemm(l) in one launch (independent halves co-scheduled)
        layer_par<<<NAGG + NGEMM, 256, 0, stream>>>(
            xc_hi, rp_a, col_c2a, xa_old,
            Wl_a2c + l * D * D, Wl_c2a + l * D * D, Wr_c2a + l * D * D, b_c2a + l * D,
            ya_bf, xa,
            (const unsigned short*)xc_hi, (const unsigned short*)xc_lo,
            Wt + l * 2 * D * D, b_a2c + l * D, Yb);
        // xc = leaky(Yb + mean ya); last layer fuses the linear head
        if (l < NLAYER - 1) {
            agg_c_bf<0><<<(NCLI + 3) / 4, 256, 0, stream>>>((const unsigned*)ya_bf, rp_c, col_a2c,
                                                            Yb, xc_hi, xc_lo, nullptr, nullptr,
                                                            nullptr, E);
        } else {
            agg_c_bf<1><<<(NCLI + 3) / 4, 256, 0, stream>>>((const unsigned*)ya_bf, rp_c, col_a2c,
                                                            Yb, nullptr, nullptr, W_lin, b_lin,
                                                            out, E);
        }
        xa_old = xa;
    }
}